// Round 7
// baseline (8939.516 us; speedup 1.0000x reference)
//
#include <hip/hip_runtime.h>

// BI-LSTM (TF LSTMCell w/ projection), T=160 B=640 F=40 HID=768 PROJ=256, 3 layers x 2 dirs.
// R12: BARRIER-FREE GEMM main loops. Evidence chain: R6 (LDS-BW) neutral, R8 (latency
// prefetch) neutral, R10 (lookahead past the barrier) +6%, R11 (B-direct, barriers kept)
// -2% => the 2-barriers-per-K-iter phase structure ITSELF is the cost (m233: stage+vmcnt+
// barrier ~72% of a 2-phase loop; every wave locked to the slowest stager 16x per kernel).
// Fix: fragment-DIRECT loads for BOTH operands, no LDS staging, no __syncthreads in the
// K-loop. B: fragment-major units (R11 layout, correctness-verified). A: the MFMA A-frag
// pattern is 16 rows x 64B contiguous (64B-aligned for lda 64/256/768) loaded straight
// from global -- L1 catches the wave-pair duplication, L2 holds weights (5x cross-block
// reuse). 12 independent waves/CU + compiler-hoistable loads (no barrier fences) = m114
// implicit-overlap regime. Gate keeps LDS ONLY for the epilogue zs exchange (33.3KB).
// Proj becomes fully barrier-free streaming (its 24 serial barriers at 1 block/CU were
// ~25% of step). Two-launch structure kept (R7/R9: kernel-boundary sync is cheapest).

typedef _Float16 h8 __attribute__((ext_vector_type(8)));
typedef float f4 __attribute__((ext_vector_type(4)));

#define T_STEPS 160
#define NB 640
#define HID 768
#define PROJ 256
#define NGATE 3072           // 4*HID

__device__ __forceinline__ float sigm(float x) { return 1.0f / (1.0f + __expf(-x)); }
__device__ __forceinline__ float tanh_fast(float x) { return 2.0f / (1.0f + __expf(-2.0f * x)) - 1.0f; }

struct GateArgs {
  const _Float16* A0[6];   // x-part source (X16 for l=0, prev-layer ring slot otherwise)
  const _Float16* A1[6];   // own h ring slot (h_{t-1} fw / h_{t+1} bw)
  const _Float16* Bw[6];   // WkT, fragment-major units (see conv_wk)
  const float*    bias[6];
  float*          cst[6];
  _Float16*       g[6];
  int w0[6];
  int lda0[6];
  int K[6];
  int act[6];
};

struct ProjArgs {
  const _Float16* G[6];    // [640][768] fp16
  const _Float16* Wp[6];   // WpT, fragment-major units
  _Float16* out[6];        // own ring write slot
  _Float16* out2[6];       // optional embed capture (layer 2, t in {0,159})
  int act[6];
};

// ---------------- gate GEMM: z = [x,h] @ WkT^T, fused bias+gates+c-update -> g ----------------
__global__ __launch_bounds__(256, 3) void gate_step(GateArgs args) {
  const int z = blockIdx.z;
  if (!args.act[z]) return;

  __shared__ __align__(16) float zs[128][65];    // epilogue exchange only (33.3KB)

  const _Float16* A0 = args.A0[z];
  const _Float16* A1 = args.A1[z];
  const _Float16* Bw = args.Bw[z];
  const int w0 = args.w0[z], lda0 = args.lda0[z], K = args.K[z];
  const int KI = K >> 6;
  const int n0 = blockIdx.x * 128;
  const int m0 = blockIdx.y * 128;
  const int tid = threadIdx.x;
  const int lane = tid & 63;
  const int wv = tid >> 6;         // 0..3
  const int wm = (wv & 1) * 64;    // wave covers rows [wm, wm+64), cols [wn, wn+64)
  const int wn = (wv >> 1) * 64;
  const int ntb = (n0 + wn) >> 4;  // first 16-row B-unit of this wave (+j for frag j)
  const int fr = lane & 15;        // frag row within 16
  const int fk = (lane >> 4) * 8;  // frag k-offset within 32

  f4 acc[4][4] = {};

  for (int ki = 0; ki < KI; ++ki) {
    // B fragments: one coalesced 16B/lane load per frag (fragment-major units, L2)
    h8 bf0[4], bf1[4];
#pragma unroll
    for (int j = 0; j < 4; ++j) {
      const _Float16* u = Bw + (((size_t)(ntb + j) * KI + ki) << 10) + lane * 8;
      bf0[j] = *(const h8*)u;
      bf1[j] = *(const h8*)(u + 512);
    }
    // A fragments direct from global: 16 rows x 64B contiguous per frag-load
#pragma unroll
    for (int kk = 0; kk < 2; ++kk) {
      const int gk = ki * 64 + kk * 32 + fk;
      const _Float16* Ab;
      int lda;
      if (gk < w0) { Ab = A0 + gk; lda = lda0; }
      else         { Ab = A1 + (gk - w0); lda = 256; }
      const h8* bf = kk ? bf1 : bf0;
#pragma unroll
      for (int i = 0; i < 4; ++i) {
        h8 af = *(const h8*)(Ab + (size_t)(m0 + wm + fr + 16 * i) * lda);
#pragma unroll
        for (int j = 0; j < 4; ++j)
          acc[i][j] = __builtin_amdgcn_mfma_f32_16x16x32_f16(af, bf[j], acc[i][j], 0, 0, 0);
      }
    }
  }

  // epilogue: two 64-col passes through zs (16 hidden units each)
  const float* bias = args.bias[z];
  float* cstate = args.cst[z];
  _Float16* gout = args.g[z];
#pragma unroll
  for (int p = 0; p < 2; ++p) {
    __syncthreads();
    if ((wv >> 1) == p) {                   // waves owning n-half p write their acc
#pragma unroll
      for (int mi = 0; mi < 4; ++mi)
#pragma unroll
        for (int ni = 0; ni < 4; ++ni)
#pragma unroll
          for (int r = 0; r < 4; ++r) {
            int row = wm + mi * 16 + ((lane >> 4) << 2) + r;  // C/D: row=(lane>>4)*4+reg
            int col = ni * 16 + (lane & 15);                  //      col=lane&15 (0..63)
            zs[row][col] = acc[mi][ni][r];
          }
    }
    __syncthreads();
    const int u0 = (n0 + p * 64) >> 2;      // first hidden unit of this pass
#pragma unroll
    for (int it = 0; it < 8; ++it) {
      int item = it * 256 + tid;            // 128 rows x 16 units
      int row = item >> 4;
      int u = item & 15;
      float zi = zs[row][4 * u + 0] + bias[0 * HID + u0 + u];
      float zj = zs[row][4 * u + 1] + bias[1 * HID + u0 + u];
      float zf = zs[row][4 * u + 2] + bias[2 * HID + u0 + u];
      float zo = zs[row][4 * u + 3] + bias[3 * HID + u0 + u];
      size_t co = (size_t)(m0 + row) * HID + u0 + u;
      float cold = cstate[co];
      float cnew = sigm(zf + 1.0f) * cold + sigm(zi) * tanh_fast(zj);  // forget_bias=1.0
      float g = sigm(zo) * tanh_fast(cnew);
      cstate[co] = cnew;
      gout[co] = (_Float16)g;
    }
  }
}

// ---------------- projection GEMM: h = g @ WpT^T ----------------
// 64x64 tile, 256 threads, K=768. Fully barrier-free: both operands fragment-direct.
__global__ __launch_bounds__(256) void proj_step(ProjArgs args) {
  const int z = blockIdx.z;
  if (!args.act[z]) return;

  const _Float16* A = args.G[z];
  const _Float16* B = args.Wp[z];
  const int n0 = blockIdx.x * 64;
  const int m0 = blockIdx.y * 64;
  const int tid = threadIdx.x;
  const int lane = tid & 63;
  const int wv = tid >> 6;
  const int wm = (wv & 1) * 32;
  const int wn = (wv >> 1) * 32;
  const int ntb = (n0 + wn) >> 4;
  const int fr = lane & 15;
  const int fk = (lane >> 4) * 8;

  f4 acc[2][2] = {};

  for (int ki = 0; ki < 12; ++ki) {
    h8 bf0[2], bf1[2];
#pragma unroll
    for (int j = 0; j < 2; ++j) {
      const _Float16* u = B + (((size_t)(ntb + j) * 12 + ki) << 10) + lane * 8;
      bf0[j] = *(const h8*)u;
      bf1[j] = *(const h8*)(u + 512);
    }
#pragma unroll
    for (int kk = 0; kk < 2; ++kk) {
      const int gk = ki * 64 + kk * 32 + fk;
      const h8* bf = kk ? bf1 : bf0;
#pragma unroll
      for (int mi = 0; mi < 2; ++mi) {
        h8 af = *(const h8*)(A + (size_t)(m0 + wm + fr + 16 * mi) * HID + gk);
        acc[mi][0] = __builtin_amdgcn_mfma_f32_16x16x32_f16(af, bf[0], acc[mi][0], 0, 0, 0);
        acc[mi][1] = __builtin_amdgcn_mfma_f32_16x16x32_f16(af, bf[1], acc[mi][1], 0, 0, 0);
      }
    }
  }

  _Float16* outp = args.out[z];
  _Float16* out2 = args.out2[z];
#pragma unroll
  for (int mi = 0; mi < 2; ++mi)
#pragma unroll
    for (int ni = 0; ni < 2; ++ni)
#pragma unroll
      for (int r = 0; r < 4; ++r) {
        int row = wm + mi * 16 + ((lane >> 4) << 2) + r;
        int col = wn + ni * 16 + (lane & 15);
        _Float16 v = (_Float16)acc[mi][ni][r];
        size_t o = (size_t)(m0 + row) * PROJ + (n0 + col);
        outp[o] = v;
        if (out2) out2[o] = v;
      }
}

// ---------------- prep kernels ----------------
__global__ void convX(const float* __restrict__ X, _Float16* __restrict__ X16, size_t total) {
  size_t i = (size_t)blockIdx.x * 256 + threadIdx.x;
  if (i >= total) return;
  int p = (int)(i & 63);
  size_t tb = i >> 6;
  float v = (p < 40) ? X[tb * 40 + p] : 0.0f;
  X16[i] = (_Float16)v;
}

// Wk fp32 [Kin+256, 3072] -> WkT fp16 fragment-major: 16-row x 64-K units of 2KB,
// unit layout [kk][lane][16B] with lane = ((k>>3)&3)*16 + (n&15), so a wave's B-frag
// load is one coalesced global_load_dwordx4. Gate-interleaved rows n'=4u+g.
// layer0 k-map: k<40 -> Wk[k]; 40..63 -> 0; 64..319 -> Wk[k-24]
__global__ void conv_wk(const float* __restrict__ Wk, _Float16* __restrict__ out,
                        int mode, int Kpad, size_t total) {
  size_t i = (size_t)blockIdx.x * 256 + threadIdx.x;
  if (i >= total) return;
  int k = (int)(i % Kpad);
  int n = (int)(i / Kpad);
  int u = n >> 2, g = n & 3;
  int col = g * HID + u;
  float v;
  if (mode == 0) {
    if (k < 40)      v = Wk[(size_t)k * NGATE + col];
    else if (k < 64) v = 0.0f;
    else             v = Wk[(size_t)(k - 24) * NGATE + col];
  } else {
    v = Wk[(size_t)k * NGATE + col];
  }
  const int KI = Kpad >> 6;
  size_t addr = (((size_t)(n >> 4) * KI + (k >> 6)) << 10)
              + (size_t)((k >> 5) & 1) * 512
              + (size_t)((((k >> 3) & 3) * 16 + (n & 15)) * 8)
              + (size_t)(k & 7);
  out[addr] = (_Float16)v;
}

// Wp fp32 [768][256] -> WpT fp16 fragment-major (rows = output cols c, K = 768)
__global__ void conv_wp(const float* __restrict__ Wp, _Float16* __restrict__ out, size_t total) {
  size_t i = (size_t)blockIdx.x * 256 + threadIdx.x;
  if (i >= total) return;
  int k = (int)(i % HID);
  int c = (int)(i / HID);
  float v = Wp[(size_t)k * PROJ + c];
  size_t addr = (((size_t)(c >> 4) * 12 + (k >> 6)) << 10)
              + (size_t)((k >> 5) & 1) * 512
              + (size_t)((((k >> 3) & 3) * 16 + (c & 15)) * 8)
              + (size_t)(k & 7);
  out[addr] = (_Float16)v;
}

// ---------------- readout ----------------
__global__ __launch_bounds__(256) void readout(const _Float16* __restrict__ E, float* __restrict__ out) {
  const size_t SL = (size_t)NB * PROJ;
  int b = blockIdx.x, tid = threadIdx.x;
  float v[2];
  float ss = 0.0f;
#pragma unroll
  for (int i = 0; i < 2; ++i) {
    int j = tid + i * 256;
    int d = j >> 8, c = j & 255;
    const _Float16* base = E + (size_t)d * 2 * SL;
    float a = (float)base[(size_t)b * PROJ + c];
    float zv = (float)base[SL + (size_t)b * PROJ + c];
    v[i] = 0.5f * (a + zv);
    ss += v[i] * v[i];
  }
#pragma unroll
  for (int off = 32; off; off >>= 1) ss += __shfl_down(ss, off);
  __shared__ float ps[4];
  if ((tid & 63) == 0) ps[tid >> 6] = ss;
  __syncthreads();
  float tot = ps[0] + ps[1] + ps[2] + ps[3];
  float nrm = rsqrtf(fmaxf(tot, 1e-12f));
  out[(size_t)b * 512 + tid] = v[0] * nrm;
  out[(size_t)b * 512 + tid + 256] = v[1] * nrm;
}

extern "C" void kernel_launch(void* const* d_in, const int* in_sizes, int n_in,
                              void* d_out, int out_size, void* d_ws, size_t ws_size,
                              hipStream_t stream) {
  (void)in_sizes; (void)n_in; (void)out_size; (void)ws_size;
  const float* X = (const float*)d_in[0];
  const float* Wk[2][3]; const float* Bi[2][3]; const float* Wp[2][3];
  for (int d = 0; d < 2; ++d)
    for (int l = 0; l < 3; ++l) {
      int base = 1 + d * 9 + l * 3;
      Wk[d][l] = (const float*)d_in[base];
      Bi[d][l] = (const float*)d_in[base + 1];
      Wp[d][l] = (const float*)d_in[base + 2];
    }

  char* ws = (char*)d_ws;
  size_t off = 0;
  auto alloc = [&](size_t bytes) -> void* {
    void* p = ws + off;
    off += (bytes + 255) & ~(size_t)255;
    return p;
  };

  const size_t SL = (size_t)NB * PROJ;    // halves per time-slot

  _Float16* X16 = (_Float16*)alloc((size_t)T_STEPS * NB * 64 * 2);
  _Float16* WkT[2][3];
  for (int d = 0; d < 2; ++d)
    for (int l = 0; l < 3; ++l)
      WkT[d][l] = (_Float16*)alloc((size_t)NGATE * (l == 0 ? 320 : 512) * 2);
  _Float16* WpT[2][3];
  for (int d = 0; d < 2; ++d)
    for (int l = 0; l < 3; ++l)
      WpT[d][l] = (_Float16*)alloc((size_t)PROJ * HID * 2);
  _Float16* Hbuf = (_Float16*)alloc(6UL * 4 * SL * 2);      // [l*2+d][4 slots][640][256]
  float* cst = (float*)alloc(6UL * NB * HID * 4);
  _Float16* gbuf = (_Float16*)alloc(6UL * NB * HID * 2);
  _Float16* embed = (_Float16*)alloc(4UL * SL * 2);         // [d][which][640][256]

  auto Hslot = [&](int l, int d, int slot) -> _Float16* {
    return Hbuf + (((size_t)(l * 2 + d) * 4) + slot) * SL;
  };

  // ---- prep ----
  {
    size_t tot = (size_t)T_STEPS * NB * 64;
    convX<<<dim3((unsigned)((tot + 255) / 256)), 256, 0, stream>>>(X, X16, tot);
  }
  for (int d = 0; d < 2; ++d)
    for (int l = 0; l < 3; ++l) {
      int Kpad = (l == 0) ? 320 : 512;
      size_t tot = (size_t)NGATE * Kpad;
      conv_wk<<<dim3((unsigned)((tot + 255) / 256)), 256, 0, stream>>>(
          Wk[d][l], WkT[d][l], (l == 0) ? 0 : 1, Kpad, tot);
      size_t totp = (size_t)PROJ * HID;
      conv_wp<<<dim3((unsigned)((totp + 255) / 256)), 256, 0, stream>>>(Wp[d][l], WpT[d][l], totp);
    }
  hipMemsetAsync(Hbuf, 0, 6UL * 4 * SL * 2, stream);        // zero rings (incl. h-init slots)
  hipMemsetAsync(cst, 0, 6UL * NB * HID * 4, stream);       // zero c state

  // ---- pipelined super-steps ----
  for (int s = 0; s <= 161; ++s) {
    GateArgs ga{};
    ProjArgs pa{};
    for (int l = 0; l < 3; ++l)
      for (int d = 0; d < 2; ++d) {
        int z = l * 2 + d;
        int t = s - l;                        // progress of layer l
        if (t < 0 || t > 159) { ga.act[z] = 0; pa.act[z] = 0; continue; }
        int tt = (d == 0) ? t : 159 - t;      // actual time index
        ga.act[z] = 1; pa.act[z] = 1;
        if (l == 0) {
          ga.A0[z] = X16 + (size_t)tt * NB * 64;
          ga.w0[z] = 64; ga.lda0[z] = 64; ga.K[z] = 320;
        } else {
          ga.A0[z] = Hslot(l - 1, d, (tt + 1) & 3);   // prev-layer output at time tt
          ga.w0[z] = 256; ga.lda0[z] = 256; ga.K[z] = 512;
        }
        int rdslot = (d == 0) ? (tt & 3) : ((tt + 2) & 3);
        ga.A1[z] = Hslot(l, d, rdslot);
        ga.Bw[z] = WkT[d][l];
        ga.bias[z] = Bi[d][l];
        ga.cst[z] = cst + (size_t)z * NB * HID;
        ga.g[z] = gbuf + (size_t)z * NB * HID;

        pa.G[z] = gbuf + (size_t)z * NB * HID;
        pa.Wp[z] = WpT[d][l];
        pa.out[z] = Hslot(l, d, (tt + 1) & 3);
        pa.out2[z] = nullptr;
        if (l == 2 && (tt == 0 || tt == 159))
          pa.out2[z] = embed + ((size_t)d * 2 + (tt == 0 ? 0 : 1)) * SL;
      }
    gate_step<<<dim3(24, 5, 6), 256, 0, stream>>>(ga);
    proj_step<<<dim3(4, 10, 6), 256, 0, stream>>>(pa);
  }

  readout<<<dim3(NB), 256, 0, stream>>>(embed, (float*)d_out);
}

// Round 8
// 7312.413 us; speedup vs baseline: 1.2225x; 1.2225x over previous
//
#include <hip/hip_runtime.h>

// BI-LSTM (TF LSTMCell w/ projection), T=160 B=640 F=40 HID=768 PROJ=256, 3 layers x 2 dirs.
// R13: ONE launch per super-step (163 total vs R10's 326). Each launch: every 3rd block
// (exactly one per CU, since 720 blocks round-robin 256 CUs at 3/CU) first executes one
// proj tile of step s-1 -- its input g comes from the PREVIOUS launch, so no wait -- then
// release-adds a per-z flag; all blocks then spin on the flags of the z's their gate
// reads, do ONE acquire (L2 inv, placed BEFORE any weight fetch), and run the R10 gate
// unchanged. Why this avoids R7/R9's failures:
//  - R9 bug: RELAXED agent polls read the poller's own stale per-XCD L2 -> poll here uses
//    SYSTEM-scope loads (sc0/sc1, cache-bypassing, fresh, NO invalidate per poll).
//  - R7 bug: 960 blocks > 768 resident slots (spinners starved producers) + acquire per
//    poll (57MB refetch/step). Here grid=720 <= 768 guaranteed co-resident by
//    __launch_bounds__(256,3) (VGPR<=168) + 36.9KB LDS (<53.3KB) => deadlock-impossible
//    regardless of dispatch order; ONE inv per block, before its weight streaming.
//  - gbuf parity-double-buffered: gate(s) writes parity s&1, proj(s-1) reads (s-1)&1.
// Gate body = R10 exactly (proven 5509us). Proj body = R10 exactly. conv_wk/conv_wp
// reverted to R10 plain layouts.

typedef _Float16 h8 __attribute__((ext_vector_type(8)));
typedef float f4 __attribute__((ext_vector_type(4)));

#define T_STEPS 160
#define NB 640
#define HID 768
#define PROJ 256
#define NGATE 3072           // 4*HID
#define SL ((size_t)NB * PROJ)

__device__ __forceinline__ float sigm(float x) { return 1.0f / (1.0f + __expf(-x)); }
__device__ __forceinline__ float tanh_fast(float x) { return 2.0f / (1.0f + __expf(-2.0f * x)) - 1.0f; }

struct SArgs {
  // gate (step s), z = l*2+d
  const _Float16* A0[6];   // x-part source (X16 for l=0, prev-layer ring slot otherwise)
  const _Float16* A1[6];   // own h ring slot
  const _Float16* Bw[6];   // WkT gate-interleaved [3072][Kpad]
  const float*    bias[6];
  float*          cst[6];
  _Float16*       gout[6]; // g output (parity s&1)
  int w0[6], lda0[6], K[6], gact[6];
  int thrOwn[6], thrPrev[6];   // flag thresholds; 0 = no wait
  // proj (step s-1)
  const _Float16* G[6];    // g input (parity (s-1)&1)
  const _Float16* Wp[6];   // [256][768]
  _Float16* hout[6];       // ring write slot
  _Float16* out2[6];       // embed capture (layer 2, t in {0,159})
  int pact[6];
  int* flags;              // [6*32] ints, cacheline-strided
};

// ---------------- gate GEMM (R10 body, unchanged) ----------------
__device__ __forceinline__ void gate_body(char* sm, const SArgs& args, int z,
                                          int bx, int by, int tid) {
  _Float16 (*As)[72] = (_Float16(*)[72])sm;      // [128][72]
  _Float16 (*Bs)[72] = (_Float16(*)[72])(sm + 18432);
  float (*zs)[65] = (float(*)[65])sm;            // [128][65] f32 (epilogue overlay)

  const _Float16* A0 = args.A0[z];
  const _Float16* A1 = args.A1[z];
  const _Float16* Bw = args.Bw[z];
  const int w0 = args.w0[z], lda0 = args.lda0[z], K = args.K[z];
  const int n0 = bx * 128;
  const int m0 = by * 128;
  const int lane = tid & 63;
  const int wv = tid >> 6;         // 0..3
  const int wm = (wv & 1) * 64;
  const int wn = (wv >> 1) * 64;

  // epilogue-operand prefetch (addresses known up-front)
  const float* bias = args.bias[z];
  float* cstate = args.cst[z];
  const int uu = tid & 15;
  const int rbase = tid >> 4;
  float cpre[2][8];
  float bpre[2][4];
#pragma unroll
  for (int p = 0; p < 2; ++p) {
    const int u0 = (n0 + p * 64) >> 2;
#pragma unroll
    for (int gg = 0; gg < 4; ++gg)
      bpre[p][gg] = bias[gg * HID + u0 + uu];
#pragma unroll
    for (int it = 0; it < 8; ++it)
      cpre[p][it] = cstate[(size_t)(m0 + it * 16 + rbase) * HID + u0 + uu];
  }

  f4 acc[4][4] = {};

  const int lr = tid >> 3;          // 0..31
  const int lkg = (tid & 7) * 8;    // k-group

  // prologue: stage k0=0 into registers
  h8 av[4], bv[4];
  {
    const int gk = lkg;
    if (gk < w0) {
#pragma unroll
      for (int r = 0; r < 4; ++r)
        av[r] = *(const h8*)(A0 + (size_t)(m0 + lr + 32 * r) * lda0 + gk);
    } else {
#pragma unroll
      for (int r = 0; r < 4; ++r)
        av[r] = *(const h8*)(A1 + (size_t)(m0 + lr + 32 * r) * 256 + (gk - w0));
    }
#pragma unroll
    for (int r = 0; r < 4; ++r)
      bv[r] = *(const h8*)(Bw + (size_t)(n0 + lr + 32 * r) * K + gk);
  }

  for (int k0 = 0; k0 < K; k0 += 64) {
    __syncthreads();                 // prior iter's LDS readers done
#pragma unroll
    for (int r = 0; r < 4; ++r) {    // vmcnt wait = last iter's regs (hidden)
      *(h8*)&As[lr + 32 * r][lkg] = av[r];
      *(h8*)&Bs[lr + 32 * r][lkg] = bv[r];
    }
    if (k0 + 64 < K) {               // next iter's loads hide under this iter's MFMAs
      const int gk = k0 + 64 + lkg;
      if (gk < w0) {
#pragma unroll
        for (int r = 0; r < 4; ++r)
          av[r] = *(const h8*)(A0 + (size_t)(m0 + lr + 32 * r) * lda0 + gk);
      } else {
#pragma unroll
        for (int r = 0; r < 4; ++r)
          av[r] = *(const h8*)(A1 + (size_t)(m0 + lr + 32 * r) * 256 + (gk - w0));
      }
#pragma unroll
      for (int r = 0; r < 4; ++r)
        bv[r] = *(const h8*)(Bw + (size_t)(n0 + lr + 32 * r) * K + gk);
    }
    __syncthreads();
#pragma unroll
    for (int kk = 0; kk < 2; ++kk) {
      const int kq = ((lane >> 4) * 8) + kk * 32;
      h8 bf[4];
#pragma unroll
      for (int j = 0; j < 4; ++j)
        bf[j] = *(const h8*)&Bs[wn + (lane & 15) + 16 * j][kq];
#pragma unroll
      for (int i = 0; i < 4; ++i) {
        h8 af = *(const h8*)&As[wm + (lane & 15) + 16 * i][kq];
#pragma unroll
        for (int j = 0; j < 4; ++j)
          acc[i][j] = __builtin_amdgcn_mfma_f32_16x16x32_f16(af, bf[j], acc[i][j], 0, 0, 0);
      }
    }
  }

  // epilogue: two 64-col passes through zs
  _Float16* gout = args.gout[z];
#pragma unroll
  for (int p = 0; p < 2; ++p) {
    __syncthreads();
    if ((wv >> 1) == p) {
#pragma unroll
      for (int mi = 0; mi < 4; ++mi)
#pragma unroll
        for (int ni = 0; ni < 4; ++ni)
#pragma unroll
          for (int r = 0; r < 4; ++r) {
            int row = wm + mi * 16 + ((lane >> 4) << 2) + r;
            int col = ni * 16 + (lane & 15);
            zs[row][col] = acc[mi][ni][r];
          }
    }
    __syncthreads();
    const int u0 = (n0 + p * 64) >> 2;
#pragma unroll
    for (int it = 0; it < 8; ++it) {
      int row = it * 16 + rbase;
      float zi = zs[row][4 * uu + 0] + bpre[p][0];
      float zj = zs[row][4 * uu + 1] + bpre[p][1];
      float zf = zs[row][4 * uu + 2] + bpre[p][2];
      float zo = zs[row][4 * uu + 3] + bpre[p][3];
      size_t co = (size_t)(m0 + row) * HID + u0 + uu;
      float cold = cpre[p][it];
      float cnew = sigm(zf + 1.0f) * cold + sigm(zi) * tanh_fast(zj);  // forget_bias=1.0
      float g = sigm(zo) * tanh_fast(cnew);
      cstate[co] = cnew;
      gout[co] = (_Float16)g;
    }
  }
}

// ---------------- projection GEMM (R10 body, unchanged) ----------------
__device__ __forceinline__ void proj_body(char* sm, const SArgs& args, int z,
                                          int bx, int by, int tid) {
  _Float16 (*As)[72] = (_Float16(*)[72])sm;            // [64][72]
  _Float16 (*Bs)[72] = (_Float16(*)[72])(sm + 9216);

  const _Float16* A = args.G[z];
  const _Float16* B = args.Wp[z];
  const int n0 = bx * 64;
  const int m0 = by * 64;
  const int lane = tid & 63;
  const int wv = tid >> 6;
  const int wm = (wv & 1) * 32;
  const int wn = (wv >> 1) * 32;

  f4 acc[2][2] = {};
  const int lr = tid >> 3;
  const int lkg = (tid & 7) * 8;

  h8 av0 = *(const h8*)(A + (size_t)(m0 + lr) * HID + lkg);
  h8 av1 = *(const h8*)(A + (size_t)(m0 + lr + 32) * HID + lkg);
  h8 bv0 = *(const h8*)(B + (size_t)(n0 + lr) * HID + lkg);
  h8 bv1 = *(const h8*)(B + (size_t)(n0 + lr + 32) * HID + lkg);

  for (int k0 = 0; k0 < HID; k0 += 64) {
    __syncthreads();
    *(h8*)&As[lr][lkg] = av0;
    *(h8*)&As[lr + 32][lkg] = av1;
    *(h8*)&Bs[lr][lkg] = bv0;
    *(h8*)&Bs[lr + 32][lkg] = bv1;
    if (k0 + 64 < HID) {
      const int gk = k0 + 64 + lkg;
      av0 = *(const h8*)(A + (size_t)(m0 + lr) * HID + gk);
      av1 = *(const h8*)(A + (size_t)(m0 + lr + 32) * HID + gk);
      bv0 = *(const h8*)(B + (size_t)(n0 + lr) * HID + gk);
      bv1 = *(const h8*)(B + (size_t)(n0 + lr + 32) * HID + gk);
    }
    __syncthreads();
    const int mr = wm + (lane & 15);
    const int nr = wn + (lane & 15);
#pragma unroll
    for (int kk = 0; kk < 2; ++kk) {
      const int kq = ((lane >> 4) * 8) + kk * 32;
      h8 a0 = *(const h8*)&As[mr][kq];
      h8 a1 = *(const h8*)&As[mr + 16][kq];
      h8 b0 = *(const h8*)&Bs[nr][kq];
      h8 b1 = *(const h8*)&Bs[nr + 16][kq];
      acc[0][0] = __builtin_amdgcn_mfma_f32_16x16x32_f16(a0, b0, acc[0][0], 0, 0, 0);
      acc[0][1] = __builtin_amdgcn_mfma_f32_16x16x32_f16(a0, b1, acc[0][1], 0, 0, 0);
      acc[1][0] = __builtin_amdgcn_mfma_f32_16x16x32_f16(a1, b0, acc[1][0], 0, 0, 0);
      acc[1][1] = __builtin_amdgcn_mfma_f32_16x16x32_f16(a1, b1, acc[1][1], 0, 0, 0);
    }
  }

  _Float16* outp = args.hout[z];
  _Float16* out2 = args.out2[z];
#pragma unroll
  for (int mi = 0; mi < 2; ++mi)
#pragma unroll
    for (int ni = 0; ni < 2; ++ni)
#pragma unroll
      for (int r = 0; r < 4; ++r) {
        int row = wm + mi * 16 + ((lane >> 4) << 2) + r;
        int col = wn + ni * 16 + (lane & 15);
        _Float16 v = (_Float16)acc[mi][ni][r];
        size_t o = (size_t)(m0 + row) * PROJ + (n0 + col);
        outp[o] = v;
        if (out2) out2[o] = v;
      }
}

// ---------------- fused step: proj(s-1) on 1 block/CU, then flag-gated gate(s) ----------------
__global__ __launch_bounds__(256, 3) void step_fused(SArgs a) {
  __shared__ __align__(16) char sm[36864];
  const int b = blockIdx.x;
  const int tid = threadIdx.x;

  // carriers: every 3rd block = exactly one per CU (720 blocks round-robin 256 CUs at 3/CU)
  if (b % 3 == 0) {
    const int pidx = b / 3;               // 0..239
    const int pz = pidx / 40, prem = pidx % 40;
    if (a.pact[pz]) {
      proj_body(sm, a, pz, prem % 4, prem / 4, tid);
      __syncthreads();                    // drains vmcnt(0): all threads' h stores complete
      if (tid == 0)
        __hip_atomic_fetch_add(&a.flags[pz * 32], 1,
                               __ATOMIC_RELEASE, __HIP_MEMORY_SCOPE_SYSTEM);
    }
  }

  const int gz = b / 120, grem = b % 120;
  if (!a.gact[gz]) return;

  // wait for this launch's proj of the z's we read. SYSTEM relaxed poll = cache-bypassing,
  // fresh, no invalidate (R9 fix). ONE acquire after, BEFORE any weight fetch (R7 fix).
  if (tid == 0) {
    const int th1 = a.thrOwn[gz], th2 = a.thrPrev[gz];
    if (th1 > 0) {
      int* f = &a.flags[gz * 32];
      while (__hip_atomic_load(f, __ATOMIC_RELAXED, __HIP_MEMORY_SCOPE_SYSTEM) < th1)
        __builtin_amdgcn_s_sleep(2);
    }
    if (th2 > 0) {
      int* f = &a.flags[(gz - 2) * 32];
      while (__hip_atomic_load(f, __ATOMIC_RELAXED, __HIP_MEMORY_SCOPE_SYSTEM) < th2)
        __builtin_amdgcn_s_sleep(2);
    }
    if ((th1 | th2) != 0)
      (void)__hip_atomic_load(&a.flags[gz * 32], __ATOMIC_ACQUIRE, __HIP_MEMORY_SCOPE_AGENT);
  }
  __syncthreads();

  gate_body(sm, a, gz, grem % 24, grem / 24, tid);
}

// ---------------- prep kernels (R10 plain layouts) ----------------
__global__ void convX(const float* __restrict__ X, _Float16* __restrict__ X16, size_t total) {
  size_t i = (size_t)blockIdx.x * 256 + threadIdx.x;
  if (i >= total) return;
  int p = (int)(i & 63);
  size_t tb = i >> 6;
  float v = (p < 40) ? X[tb * 40 + p] : 0.0f;
  X16[i] = (_Float16)v;
}

// Wk fp32 [Kin+256, 3072] -> WkT fp16 [3072][Kpad], gate-interleaved rows n'=4u+g,
// layer0 k-map: k<40 -> Wk[k]; 40..63 -> 0; 64..319 -> Wk[k-24]
__global__ void conv_wk(const float* __restrict__ Wk, _Float16* __restrict__ out,
                        int mode, int Kpad, size_t total) {
  size_t i = (size_t)blockIdx.x * 256 + threadIdx.x;
  if (i >= total) return;
  int k = (int)(i % Kpad);
  int n = (int)(i / Kpad);
  int u = n >> 2, g = n & 3;
  int col = g * HID + u;
  float v;
  if (mode == 0) {
    if (k < 40)      v = Wk[(size_t)k * NGATE + col];
    else if (k < 64) v = 0.0f;
    else             v = Wk[(size_t)(k - 24) * NGATE + col];
  } else {
    v = Wk[(size_t)k * NGATE + col];
  }
  out[i] = (_Float16)v;
}

__global__ void conv_wp(const float* __restrict__ Wp, _Float16* __restrict__ out, size_t total) {
  size_t i = (size_t)blockIdx.x * 256 + threadIdx.x;
  if (i >= total) return;
  int k = (int)(i % HID);
  int c = (int)(i / HID);
  out[i] = (_Float16)Wp[(size_t)k * PROJ + c];
}

// ---------------- readout ----------------
__global__ __launch_bounds__(256) void readout(const _Float16* __restrict__ E, float* __restrict__ out) {
  int b = blockIdx.x, tid = threadIdx.x;
  float v[2];
  float ss = 0.0f;
#pragma unroll
  for (int i = 0; i < 2; ++i) {
    int j = tid + i * 256;
    int d = j >> 8, c = j & 255;
    const _Float16* base = E + (size_t)d * 2 * SL;
    float a = (float)base[(size_t)b * PROJ + c];
    float zv = (float)base[SL + (size_t)b * PROJ + c];
    v[i] = 0.5f * (a + zv);
    ss += v[i] * v[i];
  }
#pragma unroll
  for (int off = 32; off; off >>= 1) ss += __shfl_down(ss, off);
  __shared__ float ps[4];
  if ((tid & 63) == 0) ps[tid >> 6] = ss;
  __syncthreads();
  float tot = ps[0] + ps[1] + ps[2] + ps[3];
  float nrm = rsqrtf(fmaxf(tot, 1e-12f));
  out[(size_t)b * 512 + tid] = v[0] * nrm;
  out[(size_t)b * 512 + tid + 256] = v[1] * nrm;
}

extern "C" void kernel_launch(void* const* d_in, const int* in_sizes, int n_in,
                              void* d_out, int out_size, void* d_ws, size_t ws_size,
                              hipStream_t stream) {
  (void)in_sizes; (void)n_in; (void)out_size; (void)ws_size;
  const float* X = (const float*)d_in[0];
  const float* Wk[2][3]; const float* Bi[2][3]; const float* Wp[2][3];
  for (int d = 0; d < 2; ++d)
    for (int l = 0; l < 3; ++l) {
      int base = 1 + d * 9 + l * 3;
      Wk[d][l] = (const float*)d_in[base];
      Bi[d][l] = (const float*)d_in[base + 1];
      Wp[d][l] = (const float*)d_in[base + 2];
    }

  char* ws = (char*)d_ws;
  size_t off = 0;
  auto alloc = [&](size_t bytes) -> void* {
    void* p = ws + off;
    off += (bytes + 255) & ~(size_t)255;
    return p;
  };

  _Float16* X16 = (_Float16*)alloc((size_t)T_STEPS * NB * 64 * 2);
  _Float16* WkT[2][3];
  for (int d = 0; d < 2; ++d)
    for (int l = 0; l < 3; ++l)
      WkT[d][l] = (_Float16*)alloc((size_t)NGATE * (l == 0 ? 320 : 512) * 2);
  _Float16* WpT[2][3];
  for (int d = 0; d < 2; ++d)
    for (int l = 0; l < 3; ++l)
      WpT[d][l] = (_Float16*)alloc((size_t)PROJ * HID * 2);
  _Float16* Hbuf = (_Float16*)alloc(6UL * 4 * SL * 2);      // [z][4 slots][640][256]
  float* cst = (float*)alloc(6UL * NB * HID * 4);
  _Float16* gbuf = (_Float16*)alloc(2UL * 6 * NB * HID * 2); // [parity][z][640][768]
  _Float16* embed = (_Float16*)alloc(4UL * SL * 2);         // [d][which][640][256]
  int* flags = (int*)alloc(6UL * 32 * 4);                   // per-z, cacheline-strided

  auto Hslot = [&](int l, int d, int slot) -> _Float16* {
    return Hbuf + (((size_t)(l * 2 + d) * 4) + slot) * SL;
  };
  auto Gbuf = [&](int parity, int z) -> _Float16* {
    return gbuf + ((size_t)parity * 6 + z) * NB * HID;
  };

  // ---- prep ----
  {
    size_t tot = (size_t)T_STEPS * NB * 64;
    convX<<<dim3((unsigned)((tot + 255) / 256)), 256, 0, stream>>>(X, X16, tot);
  }
  for (int d = 0; d < 2; ++d)
    for (int l = 0; l < 3; ++l) {
      int Kpad = (l == 0) ? 320 : 512;
      size_t tot = (size_t)NGATE * Kpad;
      conv_wk<<<dim3((unsigned)((tot + 255) / 256)), 256, 0, stream>>>(
          Wk[d][l], WkT[d][l], (l == 0) ? 0 : 1, Kpad, tot);
      size_t totp = (size_t)PROJ * HID;
      conv_wp<<<dim3((unsigned)((totp + 255) / 256)), 256, 0, stream>>>(Wp[d][l], WpT[d][l], totp);
    }
  hipMemsetAsync(Hbuf, 0, 6UL * 4 * SL * 2, stream);        // zero rings (incl. h-init slots)
  hipMemsetAsync(cst, 0, 6UL * NB * HID * 4, stream);       // zero c state
  hipMemsetAsync(flags, 0, 6UL * 32 * 4, stream);           // zero flags (each replay)

  // ---- fused super-steps: launch s carries proj(s-1) + gate(s) ----
  int projdone[6] = {0, 0, 0, 0, 0, 0};
  for (int s = 0; s <= 162; ++s) {
    SArgs fa{};
    fa.flags = flags;
    // proj portion: step u = s-1
    const int u = s - 1;
    for (int l = 0; l < 3; ++l)
      for (int d = 0; d < 2; ++d) {
        int z = l * 2 + d;
        if (u < 0) { fa.pact[z] = 0; continue; }
        int t = u - l;
        if (t < 0 || t > 159) { fa.pact[z] = 0; continue; }
        int tt = (d == 0) ? t : 159 - t;
        fa.pact[z] = 1;
        fa.G[z] = Gbuf(u & 1, z);
        fa.Wp[z] = WpT[d][l];
        fa.hout[z] = Hslot(l, d, (tt + 1) & 3);
        fa.out2[z] = nullptr;
        if (l == 2 && (tt == 0 || tt == 159))
          fa.out2[z] = embed + ((size_t)d * 2 + (tt == 0 ? 0 : 1)) * SL;
        projdone[z] += 40;                 // 40 proj tiles per z per step
      }
    // gate portion: step s
    if (s <= 161) {
      for (int l = 0; l < 3; ++l)
        for (int d = 0; d < 2; ++d) {
          int z = l * 2 + d;
          int t = s - l;
          if (t < 0 || t > 159) { fa.gact[z] = 0; continue; }
          int tt = (d == 0) ? t : 159 - t;
          fa.gact[z] = 1;
          if (l == 0) {
            fa.A0[z] = X16 + (size_t)tt * NB * 64;
            fa.w0[z] = 64; fa.lda0[z] = 64; fa.K[z] = 320;
          } else {
            fa.A0[z] = Hslot(l - 1, d, (tt + 1) & 3);
            fa.w0[z] = 256; fa.lda0[z] = 256; fa.K[z] = 512;
          }
          int rdslot = (d == 0) ? (tt & 3) : ((tt + 2) & 3);
          fa.A1[z] = Hslot(l, d, rdslot);
          fa.Bw[z] = WkT[d][l];
          fa.bias[z] = Bi[d][l];
          fa.cst[z] = cst + (size_t)z * NB * HID;
          fa.gout[z] = Gbuf(s & 1, z);
          fa.thrOwn[z] = projdone[z];
          fa.thrPrev[z] = (l >= 1) ? projdone[z - 2] : 0;
        }
    }
    step_fused<<<dim3(720), 256, 0, stream>>>(fa);
  }

  readout<<<dim3(NB), 256, 0, stream>>>(embed, (float*)d_out);
}

// Round 9
// 6245.309 us; speedup vs baseline: 1.4314x; 1.1709x over previous
//
#include <hip/hip_runtime.h>

// BI-LSTM (TF LSTMCell w/ projection), T=160 B=640 F=40 HID=768 PROJ=256, 3 layers x 2 dirs.
// R14: DIRECTION-PHASE-SKEWED launches -- proj rides inside the gate launch with ZERO sync.
// fw (z=0,2,4) and bw (z=1,3,5) chains are independent until readout, so:
//   L(s) = gate_fw(s) || proj_bw(s-1)      M(s) = gate_bw(s) || proj_fw(s)
// Audit: gate_fw(s)<-proj_fw(s-1) in M(s-1); proj_bw(s-1)<-gate_bw(s-1) in M(s-1);
// gate_bw(s)<-proj_bw(s-1) in L(s); proj_fw(s)<-gate_fw(s) in L(s). No intra-launch dep;
// all producer->consumer edges cross a kernel boundary (R7/R9/R13 lesson: the ONLY cheap
// coherence on this chip -- in-kernel acquires refetch ~40MB/step from L3, 48us/step).
// Grid per launch: dim3(24,5,4) = 480 blocks (z<3: gate 24x5 for 3 z's; z==3: 120 blocks
// = 3 z x 40 proj tiles). 480 <= 768 resident slots: fully co-resident, proj overlaps gate.
// Gate/proj bodies = R10 verbatim (proven 5509us): reg-lookahead K-loop, LDS staging,
// epilogue prefetch. Launch count ~325 (same as R10) but the proj kernels' serial wall
// (~5-8us/step) is absorbed into the gate launches.

typedef _Float16 h8 __attribute__((ext_vector_type(8)));
typedef float f4 __attribute__((ext_vector_type(4)));

#define T_STEPS 160
#define NB 640
#define HID 768
#define PROJ 256
#define NGATE 3072           // 4*HID
#define SL ((size_t)NB * PROJ)

__device__ __forceinline__ float sigm(float x) { return 1.0f / (1.0f + __expf(-x)); }
__device__ __forceinline__ float tanh_fast(float x) { return 2.0f / (1.0f + __expf(-2.0f * x)) - 1.0f; }

struct HArgs {
  // gates (3 z's of one direction, index i = layer)
  const _Float16* A0[3];
  const _Float16* A1[3];
  const _Float16* Bw[3];
  const float*    bias[3];
  float*          cst[3];
  _Float16*       gout[3];
  int w0[3], lda0[3], K[3], gact[3];
  // projs (3 z's of the other direction)
  const _Float16* G[3];
  const _Float16* Wp[3];
  _Float16* hout[3];
  _Float16* out2[3];
  int pact[3];
};

// ---------------- gate GEMM (R10 body) ----------------
__device__ __forceinline__ void gate_body(char* sm, const _Float16* A0, const _Float16* A1,
                                          const _Float16* Bw, const float* bias,
                                          float* cstate, _Float16* gout,
                                          int w0, int lda0, int K, int n0, int m0, int tid) {
  _Float16 (*As)[72] = (_Float16(*)[72])sm;      // [128][72]
  _Float16 (*Bs)[72] = (_Float16(*)[72])(sm + 18432);
  float (*zs)[65] = (float(*)[65])sm;            // [128][65] f32 (epilogue overlay)

  const int lane = tid & 63;
  const int wv = tid >> 6;         // 0..3
  const int wm = (wv & 1) * 64;
  const int wn = (wv >> 1) * 64;

  // epilogue-operand prefetch (addresses known up-front; hides under MFMAs)
  const int uu = tid & 15;
  const int rbase = tid >> 4;
  float cpre[2][8];
  float bpre[2][4];
#pragma unroll
  for (int p = 0; p < 2; ++p) {
    const int u0 = (n0 + p * 64) >> 2;
#pragma unroll
    for (int gg = 0; gg < 4; ++gg)
      bpre[p][gg] = bias[gg * HID + u0 + uu];
#pragma unroll
    for (int it = 0; it < 8; ++it)
      cpre[p][it] = cstate[(size_t)(m0 + it * 16 + rbase) * HID + u0 + uu];
  }

  f4 acc[4][4] = {};

  const int lr = tid >> 3;          // 0..31
  const int lkg = (tid & 7) * 8;    // k-group

  // prologue: stage k0=0 into registers
  h8 av[4], bv[4];
  {
    const int gk = lkg;
    if (gk < w0) {
#pragma unroll
      for (int r = 0; r < 4; ++r)
        av[r] = *(const h8*)(A0 + (size_t)(m0 + lr + 32 * r) * lda0 + gk);
    } else {
#pragma unroll
      for (int r = 0; r < 4; ++r)
        av[r] = *(const h8*)(A1 + (size_t)(m0 + lr + 32 * r) * 256 + (gk - w0));
    }
#pragma unroll
    for (int r = 0; r < 4; ++r)
      bv[r] = *(const h8*)(Bw + (size_t)(n0 + lr + 32 * r) * K + gk);
  }

  for (int k0 = 0; k0 < K; k0 += 64) {
    __syncthreads();                 // prior iter's LDS readers done
#pragma unroll
    for (int r = 0; r < 4; ++r) {    // vmcnt wait = last iter's regs (hidden)
      *(h8*)&As[lr + 32 * r][lkg] = av[r];
      *(h8*)&Bs[lr + 32 * r][lkg] = bv[r];
    }
    if (k0 + 64 < K) {               // next iter's loads hide under this iter's MFMAs
      const int gk = k0 + 64 + lkg;
      if (gk < w0) {
#pragma unroll
        for (int r = 0; r < 4; ++r)
          av[r] = *(const h8*)(A0 + (size_t)(m0 + lr + 32 * r) * lda0 + gk);
      } else {
#pragma unroll
        for (int r = 0; r < 4; ++r)
          av[r] = *(const h8*)(A1 + (size_t)(m0 + lr + 32 * r) * 256 + (gk - w0));
      }
#pragma unroll
      for (int r = 0; r < 4; ++r)
        bv[r] = *(const h8*)(Bw + (size_t)(n0 + lr + 32 * r) * K + gk);
    }
    __syncthreads();
#pragma unroll
    for (int kk = 0; kk < 2; ++kk) {
      const int kq = ((lane >> 4) * 8) + kk * 32;
      h8 bf[4];
#pragma unroll
      for (int j = 0; j < 4; ++j)
        bf[j] = *(const h8*)&Bs[wn + (lane & 15) + 16 * j][kq];
#pragma unroll
      for (int i = 0; i < 4; ++i) {
        h8 af = *(const h8*)&As[wm + (lane & 15) + 16 * i][kq];
#pragma unroll
        for (int j = 0; j < 4; ++j)
          acc[i][j] = __builtin_amdgcn_mfma_f32_16x16x32_f16(af, bf[j], acc[i][j], 0, 0, 0);
      }
    }
  }

  // epilogue: two 64-col passes through zs
#pragma unroll
  for (int p = 0; p < 2; ++p) {
    __syncthreads();
    if ((wv >> 1) == p) {
#pragma unroll
      for (int mi = 0; mi < 4; ++mi)
#pragma unroll
        for (int ni = 0; ni < 4; ++ni)
#pragma unroll
          for (int r = 0; r < 4; ++r) {
            int row = wm + mi * 16 + ((lane >> 4) << 2) + r;  // C/D: row=(lane>>4)*4+reg
            int col = ni * 16 + (lane & 15);                  //      col=lane&15
            zs[row][col] = acc[mi][ni][r];
          }
    }
    __syncthreads();
    const int u0 = (n0 + p * 64) >> 2;
#pragma unroll
    for (int it = 0; it < 8; ++it) {
      int row = it * 16 + rbase;
      float zi = zs[row][4 * uu + 0] + bpre[p][0];
      float zj = zs[row][4 * uu + 1] + bpre[p][1];
      float zf = zs[row][4 * uu + 2] + bpre[p][2];
      float zo = zs[row][4 * uu + 3] + bpre[p][3];
      size_t co = (size_t)(m0 + row) * HID + u0 + uu;
      float cold = cpre[p][it];
      float cnew = sigm(zf + 1.0f) * cold + sigm(zi) * tanh_fast(zj);  // forget_bias=1.0
      float g = sigm(zo) * tanh_fast(cnew);
      cstate[co] = cnew;
      gout[co] = (_Float16)g;
    }
  }
}

// ---------------- projection GEMM (R10 body) ----------------
__device__ __forceinline__ void proj_body(char* sm, const _Float16* A, const _Float16* B,
                                          _Float16* outp, _Float16* out2,
                                          int n0, int m0, int tid) {
  _Float16 (*As)[72] = (_Float16(*)[72])sm;            // [64][72]
  _Float16 (*Bs)[72] = (_Float16(*)[72])(sm + 9216);

  const int lane = tid & 63;
  const int wv = tid >> 6;
  const int wm = (wv & 1) * 32;
  const int wn = (wv >> 1) * 32;

  f4 acc[2][2] = {};
  const int lr = tid >> 3;
  const int lkg = (tid & 7) * 8;

  h8 av0 = *(const h8*)(A + (size_t)(m0 + lr) * HID + lkg);
  h8 av1 = *(const h8*)(A + (size_t)(m0 + lr + 32) * HID + lkg);
  h8 bv0 = *(const h8*)(B + (size_t)(n0 + lr) * HID + lkg);
  h8 bv1 = *(const h8*)(B + (size_t)(n0 + lr + 32) * HID + lkg);

  for (int k0 = 0; k0 < HID; k0 += 64) {
    __syncthreads();
    *(h8*)&As[lr][lkg] = av0;
    *(h8*)&As[lr + 32][lkg] = av1;
    *(h8*)&Bs[lr][lkg] = bv0;
    *(h8*)&Bs[lr + 32][lkg] = bv1;
    if (k0 + 64 < HID) {
      const int gk = k0 + 64 + lkg;
      av0 = *(const h8*)(A + (size_t)(m0 + lr) * HID + gk);
      av1 = *(const h8*)(A + (size_t)(m0 + lr + 32) * HID + gk);
      bv0 = *(const h8*)(B + (size_t)(n0 + lr) * HID + gk);
      bv1 = *(const h8*)(B + (size_t)(n0 + lr + 32) * HID + gk);
    }
    __syncthreads();
    const int mr = wm + (lane & 15);
    const int nr = wn + (lane & 15);
#pragma unroll
    for (int kk = 0; kk < 2; ++kk) {
      const int kq = ((lane >> 4) * 8) + kk * 32;
      h8 a0 = *(const h8*)&As[mr][kq];
      h8 a1 = *(const h8*)&As[mr + 16][kq];
      h8 b0 = *(const h8*)&Bs[nr][kq];
      h8 b1 = *(const h8*)&Bs[nr + 16][kq];
      acc[0][0] = __builtin_amdgcn_mfma_f32_16x16x32_f16(a0, b0, acc[0][0], 0, 0, 0);
      acc[0][1] = __builtin_amdgcn_mfma_f32_16x16x32_f16(a0, b1, acc[0][1], 0, 0, 0);
      acc[1][0] = __builtin_amdgcn_mfma_f32_16x16x32_f16(a1, b0, acc[1][0], 0, 0, 0);
      acc[1][1] = __builtin_amdgcn_mfma_f32_16x16x32_f16(a1, b1, acc[1][1], 0, 0, 0);
    }
  }

#pragma unroll
  for (int mi = 0; mi < 2; ++mi)
#pragma unroll
    for (int ni = 0; ni < 2; ++ni)
#pragma unroll
      for (int r = 0; r < 4; ++r) {
        int row = wm + mi * 16 + ((lane >> 4) << 2) + r;
        int col = wn + ni * 16 + (lane & 15);
        _Float16 v = (_Float16)acc[mi][ni][r];
        size_t o = (size_t)(m0 + row) * PROJ + (n0 + col);
        outp[o] = v;
        if (out2) out2[o] = v;
      }
}

// ---------------- half-step: 3 gates (one dir) || 3 projs (other dir), no intra-launch deps ----------------
__global__ __launch_bounds__(256, 3) void half_step(HArgs a) {
  __shared__ __align__(16) char sm[36864];
  const int tid = threadIdx.x;
  const int bz = blockIdx.z;
  if (bz < 3) {
    if (!a.gact[bz]) return;
    gate_body(sm, a.A0[bz], a.A1[bz], a.Bw[bz], a.bias[bz], a.cst[bz], a.gout[bz],
              a.w0[bz], a.lda0[bz], a.K[bz], blockIdx.x * 128, blockIdx.y * 128, tid);
  } else {
    const int idx = blockIdx.x * 5 + blockIdx.y;   // 0..119
    const int pi = idx / 40, tile = idx % 40;
    if (!a.pact[pi]) return;
    proj_body(sm, a.G[pi], a.Wp[pi], a.hout[pi], a.out2[pi],
              (tile % 4) * 64, (tile / 4) * 64, tid);
  }
}

// ---------------- prep kernels ----------------
__global__ void convX(const float* __restrict__ X, _Float16* __restrict__ X16, size_t total) {
  size_t i = (size_t)blockIdx.x * 256 + threadIdx.x;
  if (i >= total) return;
  int p = (int)(i & 63);
  size_t tb = i >> 6;
  float v = (p < 40) ? X[tb * 40 + p] : 0.0f;
  X16[i] = (_Float16)v;
}

// Wk fp32 [Kin+256, 3072] -> WkT fp16 [3072][Kpad], gate-interleaved rows n'=4u+g,
// layer0 k-map: k<40 -> Wk[k]; 40..63 -> 0; 64..319 -> Wk[k-24]
__global__ void conv_wk(const float* __restrict__ Wk, _Float16* __restrict__ out,
                        int mode, int Kpad, size_t total) {
  size_t i = (size_t)blockIdx.x * 256 + threadIdx.x;
  if (i >= total) return;
  int k = (int)(i % Kpad);
  int n = (int)(i / Kpad);
  int u = n >> 2, g = n & 3;
  int col = g * HID + u;
  float v;
  if (mode == 0) {
    if (k < 40)      v = Wk[(size_t)k * NGATE + col];
    else if (k < 64) v = 0.0f;
    else             v = Wk[(size_t)(k - 24) * NGATE + col];
  } else {
    v = Wk[(size_t)k * NGATE + col];
  }
  out[i] = (_Float16)v;
}

__global__ void conv_wp(const float* __restrict__ Wp, _Float16* __restrict__ out, size_t total) {
  size_t i = (size_t)blockIdx.x * 256 + threadIdx.x;
  if (i >= total) return;
  int k = (int)(i % HID);
  int c = (int)(i / HID);
  out[i] = (_Float16)Wp[(size_t)k * PROJ + c];
}

// ---------------- readout ----------------
__global__ __launch_bounds__(256) void readout(const _Float16* __restrict__ E, float* __restrict__ out) {
  int b = blockIdx.x, tid = threadIdx.x;
  float v[2];
  float ss = 0.0f;
#pragma unroll
  for (int i = 0; i < 2; ++i) {
    int j = tid + i * 256;
    int d = j >> 8, c = j & 255;
    const _Float16* base = E + (size_t)d * 2 * SL;
    float a = (float)base[(size_t)b * PROJ + c];
    float zv = (float)base[SL + (size_t)b * PROJ + c];
    v[i] = 0.5f * (a + zv);
    ss += v[i] * v[i];
  }
#pragma unroll
  for (int off = 32; off; off >>= 1) ss += __shfl_down(ss, off);
  __shared__ float ps[4];
  if ((tid & 63) == 0) ps[tid >> 6] = ss;
  __syncthreads();
  float tot = ps[0] + ps[1] + ps[2] + ps[3];
  float nrm = rsqrtf(fmaxf(tot, 1e-12f));
  out[(size_t)b * 512 + tid] = v[0] * nrm;
  out[(size_t)b * 512 + tid + 256] = v[1] * nrm;
}

extern "C" void kernel_launch(void* const* d_in, const int* in_sizes, int n_in,
                              void* d_out, int out_size, void* d_ws, size_t ws_size,
                              hipStream_t stream) {
  (void)in_sizes; (void)n_in; (void)out_size; (void)ws_size;
  const float* X = (const float*)d_in[0];
  const float* Wk[2][3]; const float* Bi[2][3]; const float* Wp[2][3];
  for (int d = 0; d < 2; ++d)
    for (int l = 0; l < 3; ++l) {
      int base = 1 + d * 9 + l * 3;
      Wk[d][l] = (const float*)d_in[base];
      Bi[d][l] = (const float*)d_in[base + 1];
      Wp[d][l] = (const float*)d_in[base + 2];
    }

  char* ws = (char*)d_ws;
  size_t off = 0;
  auto alloc = [&](size_t bytes) -> void* {
    void* p = ws + off;
    off += (bytes + 255) & ~(size_t)255;
    return p;
  };

  _Float16* X16 = (_Float16*)alloc((size_t)T_STEPS * NB * 64 * 2);
  _Float16* WkT[2][3];
  for (int d = 0; d < 2; ++d)
    for (int l = 0; l < 3; ++l)
      WkT[d][l] = (_Float16*)alloc((size_t)NGATE * (l == 0 ? 320 : 512) * 2);
  _Float16* WpT[2][3];
  for (int d = 0; d < 2; ++d)
    for (int l = 0; l < 3; ++l)
      WpT[d][l] = (_Float16*)alloc((size_t)PROJ * HID * 2);
  _Float16* Hbuf = (_Float16*)alloc(6UL * 4 * SL * 2);      // [z][4 slots][640][256]
  float* cst = (float*)alloc(6UL * NB * HID * 4);
  _Float16* gbuf = (_Float16*)alloc(6UL * NB * HID * 2);
  _Float16* embed = (_Float16*)alloc(4UL * SL * 2);         // [d][which][640][256]

  auto Hslot = [&](int l, int d, int slot) -> _Float16* {
    return Hbuf + (((size_t)(l * 2 + d) * 4) + slot) * SL;
  };

  // ---- prep ----
  {
    size_t tot = (size_t)T_STEPS * NB * 64;
    convX<<<dim3((unsigned)((tot + 255) / 256)), 256, 0, stream>>>(X, X16, tot);
  }
  for (int d = 0; d < 2; ++d)
    for (int l = 0; l < 3; ++l) {
      int Kpad = (l == 0) ? 320 : 512;
      size_t tot = (size_t)NGATE * Kpad;
      conv_wk<<<dim3((unsigned)((tot + 255) / 256)), 256, 0, stream>>>(
          Wk[d][l], WkT[d][l], (l == 0) ? 0 : 1, Kpad, tot);
      size_t totp = (size_t)PROJ * HID;
      conv_wp<<<dim3((unsigned)((totp + 255) / 256)), 256, 0, stream>>>(Wp[d][l], WpT[d][l], totp);
    }
  hipMemsetAsync(Hbuf, 0, 6UL * 4 * SL * 2, stream);        // zero rings (incl. h-init slots)
  hipMemsetAsync(cst, 0, 6UL * NB * HID * 4, stream);       // zero c state

  // per-(l,d,step) gate arg filler; returns active flag
  auto fill_gate = [&](HArgs& fa, int i, int l, int d, int s) {
    int z = l * 2 + d;
    int t = s - l;
    if (t < 0 || t > 159) { fa.gact[i] = 0; return; }
    int tt = (d == 0) ? t : 159 - t;
    fa.gact[i] = 1;
    if (l == 0) {
      fa.A0[i] = X16 + (size_t)tt * NB * 64;
      fa.w0[i] = 64; fa.lda0[i] = 64; fa.K[i] = 320;
    } else {
      fa.A0[i] = Hslot(l - 1, d, (tt + 1) & 3);
      fa.w0[i] = 256; fa.lda0[i] = 256; fa.K[i] = 512;
    }
    int rdslot = (d == 0) ? (tt & 3) : ((tt + 2) & 3);
    fa.A1[i] = Hslot(l, d, rdslot);
    fa.Bw[i] = WkT[d][l];
    fa.bias[i] = Bi[d][l];
    fa.cst[i] = cst + (size_t)z * NB * HID;
    fa.gout[i] = gbuf + (size_t)z * NB * HID;
  };
  auto fill_proj = [&](HArgs& fa, int i, int l, int d, int u) {
    int z = l * 2 + d;
    if (u < 0) { fa.pact[i] = 0; return; }
    int t = u - l;
    if (t < 0 || t > 159) { fa.pact[i] = 0; return; }
    int tt = (d == 0) ? t : 159 - t;
    fa.pact[i] = 1;
    fa.G[i] = gbuf + (size_t)z * NB * HID;
    fa.Wp[i] = WpT[d][l];
    fa.hout[i] = Hslot(l, d, (tt + 1) & 3);
    fa.out2[i] = nullptr;
    if (l == 2 && (tt == 0 || tt == 159))
      fa.out2[i] = embed + ((size_t)d * 2 + (tt == 0 ? 0 : 1)) * SL;
  };

  // ---- skewed half-steps ----
  for (int s = 0; s <= 162; ++s) {
    // L(s): gates fw(s) || projs bw(s-1)
    {
      HArgs fa{};
      bool any = false;
      for (int l = 0; l < 3; ++l) { fill_gate(fa, l, l, 0, s); any |= (bool)fa.gact[l]; }
      for (int l = 0; l < 3; ++l) { fill_proj(fa, l, l, 1, s - 1); any |= (bool)fa.pact[l]; }
      if (any) half_step<<<dim3(24, 5, 4), 256, 0, stream>>>(fa);
    }
    // M(s): gates bw(s) || projs fw(s)
    {
      HArgs fa{};
      bool any = false;
      for (int l = 0; l < 3; ++l) { fill_gate(fa, l, l, 1, s); any |= (bool)fa.gact[l]; }
      for (int l = 0; l < 3; ++l) { fill_proj(fa, l, l, 0, s); any |= (bool)fa.pact[l]; }
      if (any) half_step<<<dim3(24, 5, 4), 256, 0, stream>>>(fa);
    }
  }

  readout<<<dim3(NB), 256, 0, stream>>>(embed, (float*)d_out);
}

// Round 10
// 5614.514 us; speedup vs baseline: 1.5922x; 1.1124x over previous
//
#include <hip/hip_runtime.h>

// BI-LSTM (TF LSTMCell w/ projection), T=160 B=640 F=40 HID=768 PROJ=256, 3 layers x 2 dirs.
// R15: ONE barrier per K-iter. Budget from R10 vs R14: gate body ~14us, proj ~10us, fixed
// ~5us/launch; gate per-iter ~4200cy vs ~465cy MFMA => the 2-barrier single-buffer phase
// structure is the cost (m233). Fix composes two proven pieces:
//  - B fragment-direct from global in frag-major layout (R11, correctness-verified):
//    B never touches LDS; bf0 issued before the barrier, bf1 right after (hidden under kk0).
//  - A-only LDS DOUBLE buffer in the same 36.9KB (2 x [128][72]) => occupancy stays
//    3 blocks/CU AND the K-loop needs ONE __syncthreads per iter:
//    ds_write buf[k&1] -> issue A(k+1) -> barrier -> ds_read buf[k&1] + MFMA.
//    WAR across same-parity buffers is ordered by the intervening barrier (a wave's reads
//    complete before it arrives at the next barrier; writes to that parity occur only
//    after that barrier).
// R8's neutral c/bias epilogue prefetch dropped (frees ~24 VGPR; budget ~150 < 168 cap).
// Proj gets the same treatment (12 serial iters at ~1 block/CU = pure wall time).
// Two-launch-per-step structure kept (R7/R9/R13/R14: every in-kernel sync variant lost).

typedef _Float16 h8 __attribute__((ext_vector_type(8)));
typedef float f4 __attribute__((ext_vector_type(4)));

#define T_STEPS 160
#define NB 640
#define HID 768
#define PROJ 256
#define NGATE 3072           // 4*HID

__device__ __forceinline__ float sigm(float x) { return 1.0f / (1.0f + __expf(-x)); }
__device__ __forceinline__ float tanh_fast(float x) { return 2.0f / (1.0f + __expf(-2.0f * x)) - 1.0f; }

struct GateArgs {
  const _Float16* A0[6];   // x-part source (X16 for l=0, prev-layer ring slot otherwise)
  const _Float16* A1[6];   // own h ring slot (h_{t-1} fw / h_{t+1} bw)
  const _Float16* Bw[6];   // WkT, fragment-major units (see conv_wk)
  const float*    bias[6];
  float*          cst[6];
  _Float16*       g[6];
  int w0[6];
  int lda0[6];
  int K[6];
  int act[6];
};

struct ProjArgs {
  const _Float16* G[6];    // [640][768] fp16
  const _Float16* Wp[6];   // WpT, fragment-major units
  _Float16* out[6];        // own ring write slot
  _Float16* out2[6];       // optional embed capture (layer 2, t in {0,159})
  int act[6];
};

// ---------------- gate GEMM: z = [x,h] @ WkT^T, fused bias+gates+c-update -> g ----------------
__global__ __launch_bounds__(256, 3) void gate_step(GateArgs args) {
  const int z = blockIdx.z;
  if (!args.act[z]) return;

  __shared__ __align__(16) char sm[36864];       // As0 18.4KB | As1 18.4KB; epilogue overlays zs
  _Float16 (*As0)[72] = (_Float16(*)[72])sm;     // [128][72] each
  _Float16 (*As1)[72] = (_Float16(*)[72])(sm + 18432);
  float (*zs)[65] = (float(*)[65])sm;            // [128][65] f32 = 33.3KB

  const _Float16* A0 = args.A0[z];
  const _Float16* A1 = args.A1[z];
  const _Float16* Bw = args.Bw[z];
  const int w0 = args.w0[z], lda0 = args.lda0[z], K = args.K[z];
  const int KI = K >> 6;
  const int n0 = blockIdx.x * 128;
  const int m0 = blockIdx.y * 128;
  const int tid = threadIdx.x;
  const int lane = tid & 63;
  const int wv = tid >> 6;         // 0..3
  const int wm = (wv & 1) * 64;    // wave covers rows [wm, wm+64), cols [wn, wn+64)
  const int wn = (wv >> 1) * 64;
  const int ntb = (n0 + wn) >> 4;  // first 16-row B-unit of this wave (+j for frag j)
  const int fr = lane & 15;        // frag row within 16
  const int fk = (lane >> 4) * 8;  // frag k-offset within 32

  f4 acc[4][4] = {};

  const int lr = tid >> 3;          // 0..31 (stages rows lr + 32*r)
  const int lkg = (tid & 7) * 8;    // k-group 0,8,..,56

  // prologue: A(ki=0) into registers
  h8 av[4];
  {
    const int gk = lkg;
    if (gk < w0) {
#pragma unroll
      for (int r = 0; r < 4; ++r)
        av[r] = *(const h8*)(A0 + (size_t)(m0 + lr + 32 * r) * lda0 + gk);
    } else {
#pragma unroll
      for (int r = 0; r < 4; ++r)
        av[r] = *(const h8*)(A1 + (size_t)(m0 + lr + 32 * r) * 256 + (gk - w0));
    }
  }

  for (int ki = 0; ki < KI; ++ki) {
    // B kk=0 fragments: issue first (hidden under stage + barrier)
    h8 bf0[4];
#pragma unroll
    for (int j = 0; j < 4; ++j)
      bf0[j] = *(const h8*)(Bw + (((size_t)(ntb + j) * KI + ki) << 10) + lane * 8);
    // stage A(ki) into buf[ki&1]  (vmcnt wait here = loads issued LAST iter -> hidden)
    _Float16 (*As)[72] = (ki & 1) ? As1 : As0;
#pragma unroll
    for (int r = 0; r < 4; ++r)
      *(h8*)&As[lr + 32 * r][lkg] = av[r];
    // issue A(ki+1): latency hides under this iter's MFMA phase
    if (ki + 1 < KI) {
      const int gk = (ki + 1) * 64 + lkg;
      if (gk < w0) {
#pragma unroll
        for (int r = 0; r < 4; ++r)
          av[r] = *(const h8*)(A0 + (size_t)(m0 + lr + 32 * r) * lda0 + gk);
      } else {
#pragma unroll
        for (int r = 0; r < 4; ++r)
          av[r] = *(const h8*)(A1 + (size_t)(m0 + lr + 32 * r) * 256 + (gk - w0));
      }
    }
    __syncthreads();                 // buf[ki&1] full; other parity free (prior reads done)
    // B kk=1 fragments: issue now, complete under kk=0 MFMAs
    h8 bf1[4];
#pragma unroll
    for (int j = 0; j < 4; ++j)
      bf1[j] = *(const h8*)(Bw + (((size_t)(ntb + j) * KI + ki) << 10) + 512 + lane * 8);
    // MFMA phase: read A frags from buf[ki&1]
#pragma unroll
    for (int i = 0; i < 4; ++i) {
      h8 af = *(const h8*)&As[wm + fr + 16 * i][fk];
#pragma unroll
      for (int j = 0; j < 4; ++j)
        acc[i][j] = __builtin_amdgcn_mfma_f32_16x16x32_f16(af, bf0[j], acc[i][j], 0, 0, 0);
    }
#pragma unroll
    for (int i = 0; i < 4; ++i) {
      h8 af = *(const h8*)&As[wm + fr + 16 * i][fk + 32];
#pragma unroll
      for (int j = 0; j < 4; ++j)
        acc[i][j] = __builtin_amdgcn_mfma_f32_16x16x32_f16(af, bf1[j], acc[i][j], 0, 0, 0);
    }
  }

  // epilogue: two 64-col passes through zs (16 hidden units each)
  const float* bias = args.bias[z];
  float* cstate = args.cst[z];
  _Float16* gout = args.g[z];
#pragma unroll
  for (int p = 0; p < 2; ++p) {
    __syncthreads();
    if ((wv >> 1) == p) {                   // waves owning n-half p write their acc
#pragma unroll
      for (int mi = 0; mi < 4; ++mi)
#pragma unroll
        for (int ni = 0; ni < 4; ++ni)
#pragma unroll
          for (int r = 0; r < 4; ++r) {
            int row = wm + mi * 16 + ((lane >> 4) << 2) + r;  // C/D: row=(lane>>4)*4+reg
            int col = ni * 16 + (lane & 15);                  //      col=lane&15 (0..63)
            zs[row][col] = acc[mi][ni][r];
          }
    }
    __syncthreads();
    const int u0 = (n0 + p * 64) >> 2;      // first hidden unit of this pass
#pragma unroll
    for (int it = 0; it < 8; ++it) {
      int item = it * 256 + tid;            // 128 rows x 16 units
      int row = item >> 4;
      int u = item & 15;
      float zi = zs[row][4 * u + 0] + bias[0 * HID + u0 + u];
      float zj = zs[row][4 * u + 1] + bias[1 * HID + u0 + u];
      float zf = zs[row][4 * u + 2] + bias[2 * HID + u0 + u];
      float zo = zs[row][4 * u + 3] + bias[3 * HID + u0 + u];
      size_t co = (size_t)(m0 + row) * HID + u0 + u;
      float cold = cstate[co];
      float cnew = sigm(zf + 1.0f) * cold + sigm(zi) * tanh_fast(zj);  // forget_bias=1.0
      float g = sigm(zo) * tanh_fast(cnew);
      cstate[co] = cnew;
      gout[co] = (_Float16)g;
    }
  }
}

// ---------------- projection GEMM: h = g @ WpT^T ----------------
// 64x64 tile, 256 threads, K=768; A in dbuf LDS (1 barrier/iter), B fragment-direct.
__global__ __launch_bounds__(256) void proj_step(ProjArgs args) {
  const int z = blockIdx.z;
  if (!args.act[z]) return;

  __shared__ __align__(16) _Float16 As0[64][72];
  __shared__ __align__(16) _Float16 As1[64][72];

  const _Float16* A = args.G[z];
  const _Float16* B = args.Wp[z];
  const int n0 = blockIdx.x * 64;
  const int m0 = blockIdx.y * 64;
  const int tid = threadIdx.x;
  const int lane = tid & 63;
  const int wv = tid >> 6;
  const int wm = (wv & 1) * 32;
  const int wn = (wv >> 1) * 32;
  const int ntb = (n0 + wn) >> 4;
  const int fr = lane & 15;
  const int fk = (lane >> 4) * 8;

  f4 acc[2][2] = {};
  const int lr = tid >> 3;
  const int lkg = (tid & 7) * 8;

  // prologue: A(0)
  h8 av0 = *(const h8*)(A + (size_t)(m0 + lr) * HID + lkg);
  h8 av1 = *(const h8*)(A + (size_t)(m0 + lr + 32) * HID + lkg);

  for (int ki = 0; ki < 12; ++ki) {
    h8 bf0[2];
#pragma unroll
    for (int j = 0; j < 2; ++j)
      bf0[j] = *(const h8*)(B + (((size_t)(ntb + j) * 12 + ki) << 10) + lane * 8);
    _Float16 (*As)[72] = (ki & 1) ? As1 : As0;
    *(h8*)&As[lr][lkg] = av0;
    *(h8*)&As[lr + 32][lkg] = av1;
    if (ki + 1 < 12) {
      const int gk = (ki + 1) * 64 + lkg;
      av0 = *(const h8*)(A + (size_t)(m0 + lr) * HID + gk);
      av1 = *(const h8*)(A + (size_t)(m0 + lr + 32) * HID + gk);
    }
    __syncthreads();
    h8 bf1[2];
#pragma unroll
    for (int j = 0; j < 2; ++j)
      bf1[j] = *(const h8*)(B + (((size_t)(ntb + j) * 12 + ki) << 10) + 512 + lane * 8);
    const int mr = wm + fr;
    {
      h8 a0 = *(const h8*)&As[mr][fk];
      h8 a1 = *(const h8*)&As[mr + 16][fk];
      acc[0][0] = __builtin_amdgcn_mfma_f32_16x16x32_f16(a0, bf0[0], acc[0][0], 0, 0, 0);
      acc[0][1] = __builtin_amdgcn_mfma_f32_16x16x32_f16(a0, bf0[1], acc[0][1], 0, 0, 0);
      acc[1][0] = __builtin_amdgcn_mfma_f32_16x16x32_f16(a1, bf0[0], acc[1][0], 0, 0, 0);
      acc[1][1] = __builtin_amdgcn_mfma_f32_16x16x32_f16(a1, bf0[1], acc[1][1], 0, 0, 0);
      h8 a2 = *(const h8*)&As[mr][fk + 32];
      h8 a3 = *(const h8*)&As[mr + 16][fk + 32];
      acc[0][0] = __builtin_amdgcn_mfma_f32_16x16x32_f16(a2, bf1[0], acc[0][0], 0, 0, 0);
      acc[0][1] = __builtin_amdgcn_mfma_f32_16x16x32_f16(a2, bf1[1], acc[0][1], 0, 0, 0);
      acc[1][0] = __builtin_amdgcn_mfma_f32_16x16x32_f16(a3, bf1[0], acc[1][0], 0, 0, 0);
      acc[1][1] = __builtin_amdgcn_mfma_f32_16x16x32_f16(a3, bf1[1], acc[1][1], 0, 0, 0);
    }
  }

  _Float16* outp = args.out[z];
  _Float16* out2 = args.out2[z];
#pragma unroll
  for (int mi = 0; mi < 2; ++mi)
#pragma unroll
    for (int ni = 0; ni < 2; ++ni)
#pragma unroll
      for (int r = 0; r < 4; ++r) {
        int row = wm + mi * 16 + ((lane >> 4) << 2) + r;
        int col = wn + ni * 16 + (lane & 15);
        _Float16 v = (_Float16)acc[mi][ni][r];
        size_t o = (size_t)(m0 + row) * PROJ + (n0 + col);
        outp[o] = v;
        if (out2) out2[o] = v;
      }
}

// ---------------- prep kernels ----------------
__global__ void convX(const float* __restrict__ X, _Float16* __restrict__ X16, size_t total) {
  size_t i = (size_t)blockIdx.x * 256 + threadIdx.x;
  if (i >= total) return;
  int p = (int)(i & 63);
  size_t tb = i >> 6;
  float v = (p < 40) ? X[tb * 40 + p] : 0.0f;
  X16[i] = (_Float16)v;
}

// Wk fp32 [Kin+256, 3072] -> WkT fp16 fragment-major: 16-row x 64-K units of 2KB,
// unit layout [kk][lane][16B] with lane = ((k>>3)&3)*16 + (n&15), so a wave's B-frag
// load is one coalesced global_load_dwordx4. Gate-interleaved rows n'=4u+g.
// layer0 k-map: k<40 -> Wk[k]; 40..63 -> 0; 64..319 -> Wk[k-24]
__global__ void conv_wk(const float* __restrict__ Wk, _Float16* __restrict__ out,
                        int mode, int Kpad, size_t total) {
  size_t i = (size_t)blockIdx.x * 256 + threadIdx.x;
  if (i >= total) return;
  int k = (int)(i % Kpad);
  int n = (int)(i / Kpad);
  int u = n >> 2, g = n & 3;
  int col = g * HID + u;
  float v;
  if (mode == 0) {
    if (k < 40)      v = Wk[(size_t)k * NGATE + col];
    else if (k < 64) v = 0.0f;
    else             v = Wk[(size_t)(k - 24) * NGATE + col];
  } else {
    v = Wk[(size_t)k * NGATE + col];
  }
  const int KI = Kpad >> 6;
  size_t addr = (((size_t)(n >> 4) * KI + (k >> 6)) << 10)
              + (size_t)((k >> 5) & 1) * 512
              + (size_t)((((k >> 3) & 3) * 16 + (n & 15)) * 8)
              + (size_t)(k & 7);
  out[addr] = (_Float16)v;
}

// Wp fp32 [768][256] -> WpT fp16 fragment-major (rows = output cols c, K = 768)
__global__ void conv_wp(const float* __restrict__ Wp, _Float16* __restrict__ out, size_t total) {
  size_t i = (size_t)blockIdx.x * 256 + threadIdx.x;
  if (i >= total) return;
  int k = (int)(i % HID);
  int c = (int)(i / HID);
  float v = Wp[(size_t)k * PROJ + c];
  size_t addr = (((size_t)(c >> 4) * 12 + (k >> 6)) << 10)
              + (size_t)((k >> 5) & 1) * 512
              + (size_t)((((k >> 3) & 3) * 16 + (c & 15)) * 8)
              + (size_t)(k & 7);
  out[addr] = (_Float16)v;
}

// ---------------- readout ----------------
__global__ __launch_bounds__(256) void readout(const _Float16* __restrict__ E, float* __restrict__ out) {
  const size_t SL = (size_t)NB * PROJ;
  int b = blockIdx.x, tid = threadIdx.x;
  float v[2];
  float ss = 0.0f;
#pragma unroll
  for (int i = 0; i < 2; ++i) {
    int j = tid + i * 256;
    int d = j >> 8, c = j & 255;
    const _Float16* base = E + (size_t)d * 2 * SL;
    float a = (float)base[(size_t)b * PROJ + c];
    float zv = (float)base[SL + (size_t)b * PROJ + c];
    v[i] = 0.5f * (a + zv);
    ss += v[i] * v[i];
  }
#pragma unroll
  for (int off = 32; off; off >>= 1) ss += __shfl_down(ss, off);
  __shared__ float ps[4];
  if ((tid & 63) == 0) ps[tid >> 6] = ss;
  __syncthreads();
  float tot = ps[0] + ps[1] + ps[2] + ps[3];
  float nrm = rsqrtf(fmaxf(tot, 1e-12f));
  out[(size_t)b * 512 + tid] = v[0] * nrm;
  out[(size_t)b * 512 + tid + 256] = v[1] * nrm;
}

extern "C" void kernel_launch(void* const* d_in, const int* in_sizes, int n_in,
                              void* d_out, int out_size, void* d_ws, size_t ws_size,
                              hipStream_t stream) {
  (void)in_sizes; (void)n_in; (void)out_size; (void)ws_size;
  const float* X = (const float*)d_in[0];
  const float* Wk[2][3]; const float* Bi[2][3]; const float* Wp[2][3];
  for (int d = 0; d < 2; ++d)
    for (int l = 0; l < 3; ++l) {
      int base = 1 + d * 9 + l * 3;
      Wk[d][l] = (const float*)d_in[base];
      Bi[d][l] = (const float*)d_in[base + 1];
      Wp[d][l] = (const float*)d_in[base + 2];
    }

  char* ws = (char*)d_ws;
  size_t off = 0;
  auto alloc = [&](size_t bytes) -> void* {
    void* p = ws + off;
    off += (bytes + 255) & ~(size_t)255;
    return p;
  };

  const size_t SL = (size_t)NB * PROJ;    // halves per time-slot

  _Float16* X16 = (_Float16*)alloc((size_t)T_STEPS * NB * 64 * 2);
  _Float16* WkT[2][3];
  for (int d = 0; d < 2; ++d)
    for (int l = 0; l < 3; ++l)
      WkT[d][l] = (_Float16*)alloc((size_t)NGATE * (l == 0 ? 320 : 512) * 2);
  _Float16* WpT[2][3];
  for (int d = 0; d < 2; ++d)
    for (int l = 0; l < 3; ++l)
      WpT[d][l] = (_Float16*)alloc((size_t)PROJ * HID * 2);
  _Float16* Hbuf = (_Float16*)alloc(6UL * 4 * SL * 2);      // [l*2+d][4 slots][640][256]
  float* cst = (float*)alloc(6UL * NB * HID * 4);
  _Float16* gbuf = (_Float16*)alloc(6UL * NB * HID * 2);
  _Float16* embed = (_Float16*)alloc(4UL * SL * 2);         // [d][which][640][256]

  auto Hslot = [&](int l, int d, int slot) -> _Float16* {
    return Hbuf + (((size_t)(l * 2 + d) * 4) + slot) * SL;
  };

  // ---- prep ----
  {
    size_t tot = (size_t)T_STEPS * NB * 64;
    convX<<<dim3((unsigned)((tot + 255) / 256)), 256, 0, stream>>>(X, X16, tot);
  }
  for (int d = 0; d < 2; ++d)
    for (int l = 0; l < 3; ++l) {
      int Kpad = (l == 0) ? 320 : 512;
      size_t tot = (size_t)NGATE * Kpad;
      conv_wk<<<dim3((unsigned)((tot + 255) / 256)), 256, 0, stream>>>(
          Wk[d][l], WkT[d][l], (l == 0) ? 0 : 1, Kpad, tot);
      size_t totp = (size_t)PROJ * HID;
      conv_wp<<<dim3((unsigned)((totp + 255) / 256)), 256, 0, stream>>>(Wp[d][l], WpT[d][l], totp);
    }
  hipMemsetAsync(Hbuf, 0, 6UL * 4 * SL * 2, stream);        // zero rings (incl. h-init slots)
  hipMemsetAsync(cst, 0, 6UL * NB * HID * 4, stream);       // zero c state

  // ---- pipelined super-steps ----
  for (int s = 0; s <= 161; ++s) {
    GateArgs ga{};
    ProjArgs pa{};
    for (int l = 0; l < 3; ++l)
      for (int d = 0; d < 2; ++d) {
        int z = l * 2 + d;
        int t = s - l;                        // progress of layer l
        if (t < 0 || t > 159) { ga.act[z] = 0; pa.act[z] = 0; continue; }
        int tt = (d == 0) ? t : 159 - t;      // actual time index
        ga.act[z] = 1; pa.act[z] = 1;
        if (l == 0) {
          ga.A0[z] = X16 + (size_t)tt * NB * 64;
          ga.w0[z] = 64; ga.lda0[z] = 64; ga.K[z] = 320;
        } else {
          ga.A0[z] = Hslot(l - 1, d, (tt + 1) & 3);   // prev-layer output at time tt
          ga.w0[z] = 256; ga.lda0[z] = 256; ga.K[z] = 512;
        }
        int rdslot = (d == 0) ? (tt & 3) : ((tt + 2) & 3);
        ga.A1[z] = Hslot(l, d, rdslot);
        ga.Bw[z] = WkT[d][l];
        ga.bias[z] = Bi[d][l];
        ga.cst[z] = cst + (size_t)z * NB * HID;
        ga.g[z] = gbuf + (size_t)z * NB * HID;

        pa.G[z] = gbuf + (size_t)z * NB * HID;
        pa.Wp[z] = WpT[d][l];
        pa.out[z] = Hslot(l, d, (tt + 1) & 3);
        pa.out2[z] = nullptr;
        if (l == 2 && (tt == 0 || tt == 159))
          pa.out2[z] = embed + ((size_t)d * 2 + (tt == 0 ? 0 : 1)) * SL;
      }
    gate_step<<<dim3(24, 5, 6), 256, 0, stream>>>(ga);
    proj_step<<<dim3(4, 10, 6), 256, 0, stream>>>(pa);
  }

  readout<<<dim3(NB), 256, 0, stream>>>(embed, (float*)d_out);
}